// Round 1
// baseline (1046.329 us; speedup 1.0000x reference)
//
#include <hip/hip_runtime.h>
#include <hip/hip_bf16.h>

// SelMul: out[b,o] = sum_{i<=j} x[b,i]*x[b,j]*W[o, idx(i,j)]
// B=256, D=512, OUT=1024, H=131328.
// GEMM: packed(256 x 131328) @ W^T with A generated on the fly.
// Segment i: K-run [base_i, base_i+512-i), A[b,k] = x[b,i]*x[b,j] (scale folded
// at staging). BM=256 -> W read exactly once (538 MB = ~90us roofline floor).
// Latency-bound fix this round:
//   - NSPLIT 32->64 => 512 blocks => 2 blocks/CU (launch_bounds(512,4)); the
//     second block fills barrier/vmcnt stalls of the first.
//   - W prefetch depth 2 (named wvA/wvB; runtime-indexed vectors would spill):
//     HBM loads get ~2 phases in flight. A stays depth-1 (L2-hot).
// Split-K partials go to ws (plain stores), summed by a reduce kernel.

#define DDIM 512
#define ODIM 1024
#define HDIM 131328L
#define NSPLIT 64
#define AST 40   // A LDS row stride (bf16): 32 + 8 pad; 80 B rows (16B-aligned)
#define WST 40

typedef __attribute__((ext_vector_type(4))) float floatx4;
typedef __attribute__((ext_vector_type(8))) short short8;
typedef floatx4 __attribute__((aligned(4))) floatx4u;   // allow 4B-aligned dwordx4

__device__ inline floatx4 load4u(const float* p) { return *(const floatx4u*)p; }

__device__ inline unsigned short f2bf(float v) {
    return __builtin_bit_cast(unsigned short, __float2bfloat16(v));
}

__device__ inline unsigned f2bf2(float a, float b) {
    // pack two bf16 into one dword (bfloat162 isn't trivially copyable -> manual)
    return (unsigned)f2bf(a) | ((unsigned)f2bf(b) << 16);
}

// Raw barriers: do NOT drain vmcnt (prefetch stays in flight).
#define BAR_PLAIN() asm volatile("s_barrier" ::: "memory")
#define BAR_LGKM()  asm volatile("s_waitcnt lgkmcnt(0)\n\ts_barrier" ::: "memory")

__global__ __launch_bounds__(512, 4) void selmul_kernel(const float* __restrict__ x,
                                                        const float* __restrict__ W,
                                                        float* __restrict__ part) {
    __shared__ __align__(16) unsigned short A_lds[256 * AST];
    __shared__ __align__(16) unsigned short W_lds[128 * WST];

    const int t    = threadIdx.x;
    const int lane = t & 63;
    const int wave = t >> 6;            // 0..7
    const int wm   = (wave >> 1) * 64;  // 4 wave-rows
    const int wn   = (wave & 1) * 64;   // 2 wave-cols
    const int l15  = lane & 15;
    const int quad = lane >> 4;

    const int n0 = blockIdx.x * 128;    // 8 N-tiles
    const int s  = blockIdx.y;          // 0..63 k-split

    // vector staging decomposition: 4-col group c4, base row rv
    const int c4 = t & 7;               // cols c4*4 .. +3
    const int rv = t >> 3;              // 0..63

    floatx4 acc[4][4] = {};
    floatx4 av[4], wvA[2], wvB[2];
    float   xi[4];

    auto mfma_phase = [&]() {
        short8 af[4], bw[4];
        #pragma unroll
        for (int fm = 0; fm < 4; ++fm)
            af[fm] = *(const short8*)&A_lds[(wm + fm * 16 + l15) * AST + quad * 8];
        #pragma unroll
        for (int fn = 0; fn < 4; ++fn)
            bw[fn] = *(const short8*)&W_lds[(wn + fn * 16 + l15) * WST + quad * 8];
        #pragma unroll
        for (int fm = 0; fm < 4; ++fm)
            #pragma unroll
            for (int fn = 0; fn < 4; ++fn)
                acc[fm][fn] = __builtin_amdgcn_mfma_f32_16x16x32_bf16(
                    af[fm], bw[fn], acc[fm][fn], 0, 0, 0);
    };

    for (int tseg = 0; tseg < 8; ++tseg) {
        const int tt   = tseg >> 1;
        const int i    = (tseg & 1) ? (127 - s + 128 * tt) : (s + 128 * tt);
        const int len  = DDIM - i;
        const long base = (long)i * DDIM - (long)i * (i - 1) / 2;
        const int full = len >> 5;      // mask-free 32-col steps
        const int rem  = len & 31;      // masked tail columns

        // per-segment scale column, rows rv+64e (L2-hot scalar loads)
        #pragma unroll
        for (int e = 0; e < 4; ++e)
            xi[e] = x[(rv + 64 * e) * DDIM + i];

        if (full > 0) {
            const float* axp = x + rv * DDIM + i + c4 * 4;
            const float* wpp = W + (long)(n0 + rv) * HDIM + base + c4 * 4;
            // prefetch step 0 (A first: L2-fast, consumed first; W: HBM)
            #pragma unroll
            for (int e = 0; e < 4; ++e) av[e] = load4u(axp + e * 64 * DDIM);
            #pragma unroll
            for (int e = 0; e < 2; ++e) wvA[e] = load4u(wpp + (long)e * 64 * HDIM);
            if (full > 1) {
                #pragma unroll
                for (int e = 0; e < 2; ++e) wvB[e] = load4u(wpp + 32 + (long)e * 64 * HDIM);
            }
            axp += 32; wpp += 64;

            // one pipelined step; wvp = W double-buffer for this parity
            auto step_body = [&](floatx4 (&wvp)[2], int st) {
                BAR_PLAIN();   // prev MFMA phase's LDS reads have landed (lgkm waits)
                // ---- store phase: convert prefetched regs -> LDS (waits vmcnt here)
                #pragma unroll
                for (int e = 0; e < 4; ++e) {
                    const int row = rv + 64 * e;
                    floatx4 v = av[e];
                    const float sc = xi[e];
                    uint2 p;
                    p.x = f2bf2(v.x * sc, v.y * sc);
                    p.y = f2bf2(v.z * sc, v.w * sc);
                    *(uint2*)&A_lds[row * AST + c4 * 4] = p;
                }
                #pragma unroll
                for (int e = 0; e < 2; ++e) {
                    const int row = rv + 64 * e;
                    floatx4 v = wvp[e];
                    uint2 p;
                    p.x = f2bf2(v.x, v.y);
                    p.y = f2bf2(v.z, v.w);
                    *(uint2*)&W_lds[row * WST + c4 * 4] = p;
                }
                // ---- issue next loads; they stay in flight through MFMA phases
                if (st + 1 < full) {   // A for next step (depth 1, L2-hot)
                    #pragma unroll
                    for (int e = 0; e < 4; ++e) av[e] = load4u(axp + e * 64 * DDIM);
                    axp += 32;
                }
                if (st + 2 < full) {   // W for step st+2 (depth 2, HBM)
                    #pragma unroll
                    for (int e = 0; e < 2; ++e) wvp[e] = load4u(wpp + (long)e * 64 * HDIM);
                    wpp += 32;
                }
                BAR_LGKM();    // LDS writes visible; vmcnt NOT drained
                mfma_phase();
            };

            for (int st = 0; st < full; st += 2) {
                step_body(wvA, st);
                if (st + 1 < full) step_body(wvB, st + 1);
            }
        }

        if (rem) {
            // tail step: scalar masked staging (rare, correctness-first)
            const int jj = t & 31;
            const int rb = t >> 5;          // 0..15
            const int j0 = i + full * 32;
            const bool valid = jj < rem;
            const int j = valid ? (j0 + jj) : i;   // in-bounds col
            const long kc = base + (long)full * 32;
            BAR_PLAIN();
            #pragma unroll
            for (int e = 0; e < 16; ++e) {
                const int m = rb + 16 * e;
                float a = valid ? x[m * DDIM + j] * x[m * DDIM + i] : 0.0f;
                A_lds[m * AST + jj] = f2bf(a);
            }
            #pragma unroll
            for (int e = 0; e < 8; ++e) {
                const int n = rb + 16 * e;
                const long ks = valid ? (kc + jj) : base;
                W_lds[n * WST + jj] = f2bf(W[(long)(n0 + n) * HDIM + ks]);
            }
            BAR_LGKM();
            mfma_phase();
        }
    }

    // plain (non-atomic) partial store: part[s][row][col]
    float* po = part + (long)s * (256 * ODIM);
    #pragma unroll
    for (int fm = 0; fm < 4; ++fm) {
        const int row = wm + fm * 16 + quad * 4;
        #pragma unroll
        for (int fn = 0; fn < 4; ++fn) {
            const int col = n0 + wn + fn * 16 + l15;
            #pragma unroll
            for (int r = 0; r < 4; ++r)
                po[(row + r) * ODIM + col] = acc[fm][fn][r];
        }
    }
}

__global__ __launch_bounds__(256) void reduce_kernel(const float* __restrict__ part,
                                                     float* __restrict__ out) {
    const int gid = blockIdx.x * 256 + threadIdx.x;   // 0..65535 float4s
    floatx4 a0 = {}, a1 = {}, a2 = {}, a3 = {};
    #pragma unroll
    for (int sp = 0; sp < NSPLIT; sp += 4) {
        a0 += *(const floatx4*)(part + (long)(sp + 0) * (256 * ODIM) + gid * 4);
        a1 += *(const floatx4*)(part + (long)(sp + 1) * (256 * ODIM) + gid * 4);
        a2 += *(const floatx4*)(part + (long)(sp + 2) * (256 * ODIM) + gid * 4);
        a3 += *(const floatx4*)(part + (long)(sp + 3) * (256 * ODIM) + gid * 4);
    }
    *(floatx4*)(out + gid * 4) = (a0 + a1) + (a2 + a3);
}

extern "C" void kernel_launch(void* const* d_in, const int* in_sizes, int n_in,
                              void* d_out, int out_size, void* d_ws, size_t ws_size,
                              hipStream_t stream) {
    const float* x = (const float*)d_in[0];   // (256, 512) fp32
    const float* W = (const float*)d_in[1];   // (1024, 131328) fp32
    float* out  = (float*)d_out;              // (256, 1024) fp32
    float* part = (float*)d_ws;               // 64 x 256 x 1024 fp32 = 64 MB

    hipLaunchKernelGGL(selmul_kernel, dim3(8, NSPLIT), dim3(512), 0, stream, x, W, part);
    hipLaunchKernelGGL(reduce_kernel, dim3(256), dim3(256), 0, stream, part, out);
}

// Round 2
// 906.383 us; speedup vs baseline: 1.1544x; 1.1544x over previous
//
#include <hip/hip_runtime.h>
#include <hip/hip_bf16.h>

// SelMul: out[b,o] = sum_{i<=j} x[b,i]*x[b,j]*W[o, idx(i,j)]
// B=256, D=512, OUT=1024, H=131328.
// GEMM: packed(256 x 131328) @ W^T with A generated on the fly.
// Segment i: K-run [base_i, base_i+512-i), A[b,k] = x[b,i]*x[b,j] (scale folded
// at staging). BM=256 -> W read exactly once (538 MB = ~90us roofline floor).
// Round-1 lesson: launch_bounds(512,4) with BN=128 (acc=64 regs) spilled to
// scratch (VGPR 64, FETCH+WRITE +400MB each, dur +56%). This round keeps
// 2 blocks/CU but halves the tile: BN=64 (16 x-tiles, NSPLIT=32, 512 blocks),
// acc=32 regs, W depth-2 prefetch = 8 regs -> fits 128-reg budget, no spill.
// Split-K partials go to ws (plain stores), summed by a reduce kernel.

#define DDIM 512
#define ODIM 1024
#define HDIM 131328L
#define NSPLIT 32
#define AST 40   // A LDS row stride (bf16): 32 + 8 pad; 80 B rows (16B-aligned)
#define WST 40

typedef __attribute__((ext_vector_type(4))) float floatx4;
typedef __attribute__((ext_vector_type(8))) short short8;
typedef floatx4 __attribute__((aligned(4))) floatx4u;   // allow 4B-aligned dwordx4

__device__ inline floatx4 load4u(const float* p) { return *(const floatx4u*)p; }

__device__ inline unsigned short f2bf(float v) {
    return __builtin_bit_cast(unsigned short, __float2bfloat16(v));
}

__device__ inline unsigned f2bf2(float a, float b) {
    // pack two bf16 into one dword (bfloat162 isn't trivially copyable -> manual)
    return (unsigned)f2bf(a) | ((unsigned)f2bf(b) << 16);
}

// Raw barriers: do NOT drain vmcnt (prefetch stays in flight).
#define BAR_PLAIN() asm volatile("s_barrier" ::: "memory")
#define BAR_LGKM()  asm volatile("s_waitcnt lgkmcnt(0)\n\ts_barrier" ::: "memory")

__global__ __launch_bounds__(512, 4) void selmul_kernel(const float* __restrict__ x,
                                                        const float* __restrict__ W,
                                                        float* __restrict__ part) {
    __shared__ __align__(16) unsigned short A_lds[256 * AST];
    __shared__ __align__(16) unsigned short W_lds[64 * WST];

    const int t    = threadIdx.x;
    const int lane = t & 63;
    const int wave = t >> 6;            // 0..7
    const int wm   = (wave >> 1) * 64;  // 4 wave-rows (64 rows each)
    const int wn   = (wave & 1) * 32;   // 2 wave-cols (32 cols each)
    const int l15  = lane & 15;
    const int quad = lane >> 4;

    const int n0 = blockIdx.x * 64;     // 16 N-tiles
    const int s  = blockIdx.y;          // 0..31 k-split

    // vector staging decomposition: 4-col group c4, base row rv
    const int c4 = t & 7;               // cols c4*4 .. +3
    const int rv = t >> 3;              // 0..63

    floatx4 acc[4][2] = {};
    floatx4 av[4], wvA, wvB;
    float   xi[4];

    auto mfma_phase = [&]() {
        short8 af[4], bw[2];
        #pragma unroll
        for (int fm = 0; fm < 4; ++fm)
            af[fm] = *(const short8*)&A_lds[(wm + fm * 16 + l15) * AST + quad * 8];
        #pragma unroll
        for (int fn = 0; fn < 2; ++fn)
            bw[fn] = *(const short8*)&W_lds[(wn + fn * 16 + l15) * WST + quad * 8];
        #pragma unroll
        for (int fm = 0; fm < 4; ++fm)
            #pragma unroll
            for (int fn = 0; fn < 2; ++fn)
                acc[fm][fn] = __builtin_amdgcn_mfma_f32_16x16x32_bf16(
                    af[fm], bw[fn], acc[fm][fn], 0, 0, 0);
    };

    for (int tseg = 0; tseg < 16; ++tseg) {
        const int tt   = tseg >> 1;
        const int i    = (tseg & 1) ? (63 - s + 64 * tt) : (s + 64 * tt);
        const int len  = DDIM - i;
        const long base = (long)i * DDIM - (long)i * (i - 1) / 2;
        const int full = len >> 5;      // mask-free 32-col steps
        const int rem  = len & 31;      // masked tail columns

        // per-segment scale column, rows rv+64e (L2-hot scalar loads)
        #pragma unroll
        for (int e = 0; e < 4; ++e)
            xi[e] = x[(rv + 64 * e) * DDIM + i];

        if (full > 0) {
            const float* axp = x + rv * DDIM + i + c4 * 4;
            const float* wpp = W + (long)(n0 + rv) * HDIM + base + c4 * 4;
            // prefetch step 0 (A first: L2-fast, consumed first; W: HBM)
            #pragma unroll
            for (int e = 0; e < 4; ++e) av[e] = load4u(axp + e * 64 * DDIM);
            wvA = load4u(wpp);
            if (full > 1) wvB = load4u(wpp + 32);
            axp += 32; wpp += 64;

            // one pipelined step; wvp = W double-buffer for this parity
            auto step_body = [&](floatx4& wvp, int st) {
                BAR_PLAIN();   // prev MFMA phase's LDS reads have landed (lgkm waits)
                // ---- store phase: convert prefetched regs -> LDS (waits vmcnt here)
                #pragma unroll
                for (int e = 0; e < 4; ++e) {
                    const int row = rv + 64 * e;
                    floatx4 v = av[e];
                    const float sc = xi[e];
                    uint2 p;
                    p.x = f2bf2(v.x * sc, v.y * sc);
                    p.y = f2bf2(v.z * sc, v.w * sc);
                    *(uint2*)&A_lds[row * AST + c4 * 4] = p;
                }
                {
                    floatx4 v = wvp;
                    uint2 p;
                    p.x = f2bf2(v.x, v.y);
                    p.y = f2bf2(v.z, v.w);
                    *(uint2*)&W_lds[rv * WST + c4 * 4] = p;
                }
                // ---- issue next loads; they stay in flight through MFMA phases
                if (st + 1 < full) {   // A for next step (depth 1, L2-hot)
                    #pragma unroll
                    for (int e = 0; e < 4; ++e) av[e] = load4u(axp + e * 64 * DDIM);
                    axp += 32;
                }
                if (st + 2 < full) {   // W for step st+2 (depth 2, HBM)
                    wvp = load4u(wpp);
                    wpp += 32;
                }
                BAR_LGKM();    // LDS writes visible; vmcnt NOT drained
                mfma_phase();
            };

            for (int st = 0; st < full; st += 2) {
                step_body(wvA, st);
                if (st + 1 < full) step_body(wvB, st + 1);
            }
        }

        if (rem) {
            // tail step: scalar masked staging (rare, correctness-first)
            const int jj = t & 31;
            const int rb = t >> 5;          // 0..15
            const int j0 = i + full * 32;
            const bool valid = jj < rem;
            const int j = valid ? (j0 + jj) : i;   // in-bounds col
            const long kc = base + (long)full * 32;
            BAR_PLAIN();
            #pragma unroll
            for (int e = 0; e < 16; ++e) {
                const int m = rb + 16 * e;
                float a = valid ? x[m * DDIM + j] * x[m * DDIM + i] : 0.0f;
                A_lds[m * AST + jj] = f2bf(a);
            }
            #pragma unroll
            for (int e = 0; e < 4; ++e) {
                const int n = rb + 16 * e;
                const long ks = valid ? (kc + jj) : base;
                W_lds[n * WST + jj] = f2bf(W[(long)(n0 + n) * HDIM + ks]);
            }
            BAR_LGKM();
            mfma_phase();
        }
    }

    // plain (non-atomic) partial store: part[s][row][col]
    float* po = part + (long)s * (256 * ODIM);
    #pragma unroll
    for (int fm = 0; fm < 4; ++fm) {
        const int row = wm + fm * 16 + quad * 4;
        #pragma unroll
        for (int fn = 0; fn < 2; ++fn) {
            const int col = n0 + wn + fn * 16 + l15;
            #pragma unroll
            for (int r = 0; r < 4; ++r)
                po[(row + r) * ODIM + col] = acc[fm][fn][r];
        }
    }
}

__global__ __launch_bounds__(256) void reduce_kernel(const float* __restrict__ part,
                                                     float* __restrict__ out) {
    const int gid = blockIdx.x * 256 + threadIdx.x;   // 0..65535 float4s
    floatx4 a0 = {}, a1 = {}, a2 = {}, a3 = {};
    #pragma unroll
    for (int sp = 0; sp < NSPLIT; sp += 4) {
        a0 += *(const floatx4*)(part + (long)(sp + 0) * (256 * ODIM) + gid * 4);
        a1 += *(const floatx4*)(part + (long)(sp + 1) * (256 * ODIM) + gid * 4);
        a2 += *(const floatx4*)(part + (long)(sp + 2) * (256 * ODIM) + gid * 4);
        a3 += *(const floatx4*)(part + (long)(sp + 3) * (256 * ODIM) + gid * 4);
    }
    *(floatx4*)(out + gid * 4) = (a0 + a1) + (a2 + a3);
}

extern "C" void kernel_launch(void* const* d_in, const int* in_sizes, int n_in,
                              void* d_out, int out_size, void* d_ws, size_t ws_size,
                              hipStream_t stream) {
    const float* x = (const float*)d_in[0];   // (256, 512) fp32
    const float* W = (const float*)d_in[1];   // (1024, 131328) fp32
    float* out  = (float*)d_out;              // (256, 1024) fp32
    float* part = (float*)d_ws;               // 32 x 256 x 1024 fp32 = 32 MB

    hipLaunchKernelGGL(selmul_kernel, dim3(16, NSPLIT), dim3(512), 0, stream, x, W, part);
    hipLaunchKernelGGL(reduce_kernel, dim3(256), dim3(256), 0, stream, part, out);
}